// Round 3
// baseline (125.752 us; speedup 1.0000x reference)
//
#include <hip/hip_runtime.h>
#include <hip/hip_cooperative_groups.h>
#include <math.h>

namespace cg = cooperative_groups;

#define N_ROWS 8192   // SIZE
#define N_COLS 1024   // M
#define NBLK   256    // == #CUs, 1 block/CU
#define NTHR   1024
// Per block: 32 rows x 1024 cols. Per thread: 8 rows x 4 cols (float4).
// Chunk = 8 rows -> 1024 chunks total (4 per block).

__global__ __launch_bounds__(NTHR, 4) void fused_logmatexp(
    const float* __restrict__ x, const float* __restrict__ diag,
    float* __restrict__ pm, float* __restrict__ ps,   // [1024][N_COLS] chunk partials
    float* __restrict__ mB, float* __restrict__ T,    // [N_COLS]
    float* __restrict__ out)
{
    cg::grid_group grid = cg::this_grid();

    const int t    = threadIdx.x;
    const int b    = blockIdx.x;
    const int cgi  = t & 255;          // column-group index
    const int col0 = cgi * 4;
    const int rg   = t >> 8;           // row-group within block (0..3)
    const int row0 = b * 32 + rg * 8;
    const int ch   = b * 4 + rg;       // global chunk id (0..1023)

    // ---------- Phase 1: load x slice into registers, column partials ----------
    float4 v[8];
#pragma unroll
    for (int k = 0; k < 8; ++k)
        v[k] = *reinterpret_cast<const float4*>(x + (size_t)(row0 + k) * N_COLS + col0);

    float4 m4 = v[0];
#pragma unroll
    for (int k = 1; k < 8; ++k) {
        m4.x = fmaxf(m4.x, v[k].x); m4.y = fmaxf(m4.y, v[k].y);
        m4.z = fmaxf(m4.z, v[k].z); m4.w = fmaxf(m4.w, v[k].w);
    }
    float4 s4 = make_float4(0.f, 0.f, 0.f, 0.f);
#pragma unroll
    for (int k = 0; k < 8; ++k) {
        s4.x += __expf(v[k].x - m4.x); s4.y += __expf(v[k].y - m4.y);
        s4.z += __expf(v[k].z - m4.z); s4.w += __expf(v[k].w - m4.w);
    }
    *reinterpret_cast<float4*>(pm + (size_t)ch * N_COLS + col0) = m4;
    *reinterpret_cast<float4*>(ps + (size_t)ch * N_COLS + col0) = s4;

    grid.sync();

    // ---------- Phase 2: block b merges columns 4b .. 4b+3 ----------
    {
        const int g   = t >> 8;          // which of the 4 columns
        const int sub = t & 255;         // 256 threads per column
        const int col = 4 * b + g;
        const int wid  = t >> 6;         // wave 0..15 (waves 4g..4g+3 belong to col g)
        const int lane = t & 63;

        float mm[4], ss[4];
#pragma unroll
        for (int i = 0; i < 4; ++i) {
            mm[i] = pm[(size_t)(sub * 4 + i) * N_COLS + col];
            ss[i] = ps[(size_t)(sub * 4 + i) * N_COLS + col];
        }
        float M = fmaxf(fmaxf(mm[0], mm[1]), fmaxf(mm[2], mm[3]));
#pragma unroll
        for (int off = 32; off; off >>= 1) M = fmaxf(M, __shfl_down(M, off));

        __shared__ float redm[16];
        __shared__ float reds[16];
        if (lane == 0) redm[wid] = M;
        __syncthreads();
        M = fmaxf(fmaxf(redm[4 * g + 0], redm[4 * g + 1]),
                  fmaxf(redm[4 * g + 2], redm[4 * g + 3]));

        float ts = 0.f;
#pragma unroll
        for (int i = 0; i < 4; ++i) ts += ss[i] * __expf(mm[i] - M);
#pragma unroll
        for (int off = 32; off; off >>= 1) ts += __shfl_down(ts, off);
        if (lane == 0) reds[wid] = ts;
        __syncthreads();
        if (sub == 0) {
            mB[col] = M;
            T[col]  = reds[4 * g + 0] + reds[4 * g + 1] +
                      reds[4 * g + 2] + reds[4 * g + 3];
        }
    }

    grid.sync();

    // ---------- Phase 3: finalize from registers ----------
    const float4 mj = *reinterpret_cast<const float4*>(mB + col0);
    const float4 Tj = *reinterpret_cast<const float4*>(T  + col0);

#pragma unroll
    for (int k = 0; k < 8; ++k) {
        const float di = diag[row0 + k];
        const float rA = fmaxf(di, 0.f);
        const float a  = __expf(-fabsf(di));
        const float edd = (di > 0.f) ? 1.f : a;   // exp(di - rA)
        const float er  = (di > 0.f) ? a : 1.f;   // exp(-rA)
        float4 o;
        {
            const float e = __expf(v[k].x - mj.x);
            o.x = rA + mj.x + __logf(edd * e + er * (Tj.x - e));
        }
        {
            const float e = __expf(v[k].y - mj.y);
            o.y = rA + mj.y + __logf(edd * e + er * (Tj.y - e));
        }
        {
            const float e = __expf(v[k].z - mj.z);
            o.z = rA + mj.z + __logf(edd * e + er * (Tj.z - e));
        }
        {
            const float e = __expf(v[k].w - mj.w);
            o.w = rA + mj.w + __logf(edd * e + er * (Tj.w - e));
        }
        *reinterpret_cast<float4*>(out + (size_t)(row0 + k) * N_COLS + col0) = o;
    }
}

extern "C" void kernel_launch(void* const* d_in, const int* in_sizes, int n_in,
                              void* d_out, int out_size, void* d_ws, size_t ws_size,
                              hipStream_t stream) {
    const float* x    = (const float*)d_in[0];   // [8192, 1024] f32
    const float* diag = (const float*)d_in[1];   // [8192] f32
    float* out = (float*)d_out;                  // [8192, 1024] f32
    float* ws  = (float*)d_ws;

    float* pm = ws;                          // 1024 * N_COLS
    float* ps = pm + 1024 * N_COLS;          // 1024 * N_COLS
    float* mB = ps + 1024 * N_COLS;          // N_COLS
    float* T  = mB + N_COLS;                 // N_COLS
    // ws use: (2*1024*1024 + 2048) * 4 B ~= 8.4 MB

    void* args[] = { (void*)&x, (void*)&diag, (void*)&pm, (void*)&ps,
                     (void*)&mB, (void*)&T, (void*)&out };
    hipLaunchCooperativeKernel((const void*)fused_logmatexp,
                               dim3(NBLK), dim3(NTHR), args, 0, stream);
}

// Round 4
// 26.560 us; speedup vs baseline: 4.7346x; 4.7346x over previous
//
#include <hip/hip_runtime.h>
#include <math.h>

#define N_ROWS 8192   // SIZE
#define N_COLS 1024   // M

// K1: ps[b][j] = sum over rows [32b, 32b+32) of exp(x[i][j]).
// Grid: 256 blocks x 1024 threads. Thread (rg = t>>8, cgi = t&255) owns
// 8 rows x 4 cols (float4). LDS reduce across the 4 row-groups.
__global__ __launch_bounds__(1024) void colsum_part(
    const float* __restrict__ x, float* __restrict__ ps) {
    const int b    = blockIdx.x;
    const int t    = threadIdx.x;
    const int col0 = (t & 255) * 4;
    const int rg   = t >> 8;            // 0..3
    const int row0 = b * 32 + rg * 8;

    float4 s4 = make_float4(0.f, 0.f, 0.f, 0.f);
#pragma unroll
    for (int k = 0; k < 8; ++k) {
        const float4 v = *reinterpret_cast<const float4*>(
            x + (size_t)(row0 + k) * N_COLS + col0);
        s4.x += __expf(v.x); s4.y += __expf(v.y);
        s4.z += __expf(v.z); s4.w += __expf(v.w);
    }

    __shared__ float red[4][N_COLS];    // 16 KB
    *reinterpret_cast<float4*>(&red[rg][col0]) = s4;   // contiguous per wave: no conflicts
    __syncthreads();
    // thread t sums column t across the 4 row-groups (stride-4B reads: conflict-free)
    ps[(size_t)b * N_COLS + t] = red[0][t] + red[1][t] + red[2][t] + red[3][t];
}

// K2: block = (cs = col-stripe 0..3, rb = row-block 0..63).
// Phase A: S[c] = sum over 256 chunks of ps[chunk][cs*256 + c]  (coalesced).
// Phase B: finalize rows [rb*128, rb*128+128) x cols [cs*256, cs*256+256):
//   out = log(S[j] + (exp(diag[i]) - 1) * exp(x[i,j]))
__global__ __launch_bounds__(1024) void merge_finalize(
    const float* __restrict__ x, const float* __restrict__ diag,
    const float* __restrict__ ps, float* __restrict__ out) {
    const int cs = blockIdx.x & 3;
    const int rb = blockIdx.x >> 2;
    const int c0 = cs * 256;
    const int t  = threadIdx.x;

    __shared__ float red[4][256];       // 4 KB
    __shared__ float S[256];            // 1 KB
    {
        const int cg = t >> 8;          // chunk-group 0..3 (64 chunks each)
        const int c  = t & 255;
        float s = 0.f;
#pragma unroll 8
        for (int k = 0; k < 64; ++k)
            s += ps[(size_t)(cg * 64 + k) * N_COLS + c0 + c];
        red[cg][c] = s;
    }
    __syncthreads();
    if (t < 256) S[t] = red[0][t] + red[1][t] + red[2][t] + red[3][t];
    __syncthreads();

    const int lane = t & 63;
    const int w    = t >> 6;            // 16 waves, 8 rows each
    const int r0   = rb * 128 + w * 8;
    const float4 Sj = *reinterpret_cast<const float4*>(&S[4 * lane]);

#pragma unroll
    for (int k = 0; k < 8; ++k) {
        const int row = r0 + k;
        const float E = __expf(diag[row]) - 1.f;   // wave-uniform: scalar path
        const size_t off = (size_t)row * N_COLS + c0 + 4 * lane;
        const float4 v = *reinterpret_cast<const float4*>(x + off);
        float4 o;
        o.x = __logf(fmaf(E, __expf(v.x), Sj.x));
        o.y = __logf(fmaf(E, __expf(v.y), Sj.y));
        o.z = __logf(fmaf(E, __expf(v.z), Sj.z));
        o.w = __logf(fmaf(E, __expf(v.w), Sj.w));
        *reinterpret_cast<float4*>(out + off) = o;
    }
}

extern "C" void kernel_launch(void* const* d_in, const int* in_sizes, int n_in,
                              void* d_out, int out_size, void* d_ws, size_t ws_size,
                              hipStream_t stream) {
    const float* x    = (const float*)d_in[0];   // [8192, 1024] f32
    const float* diag = (const float*)d_in[1];   // [8192] f32
    float* out = (float*)d_out;                  // [8192, 1024] f32
    float* ps  = (float*)d_ws;                   // [256][1024] f32 = 1 MB

    colsum_part<<<256, 1024, 0, stream>>>(x, ps);
    merge_finalize<<<256, 1024, 0, stream>>>(x, diag, ps, out);
}